// Round 20
// baseline (243.936 us; speedup 1.0000x reference)
//
#include <hip/hip_runtime.h>
#include <hip/hip_bf16.h>

#define NBATCH 32
#define NG 1024
#define DM 256

typedef short bf16x8 __attribute__((ext_vector_type(8)));
typedef float f32x4 __attribute__((ext_vector_type(4)));
typedef unsigned short u16x4 __attribute__((ext_vector_type(4)));
typedef unsigned short u16x8 __attribute__((ext_vector_type(8)));

static __device__ __forceinline__ unsigned short f2bf(float f) {
    __hip_bfloat16 h = __float2bfloat16(f);
    return *reinterpret_cast<unsigned short*>(&h);
}
static __device__ __forceinline__ float bf2f(unsigned short u) {
    unsigned int x = ((unsigned int)u) << 16;
    return *reinterpret_cast<float*>(&x);
}

// async global->LDS, 16B per lane. LDS dest wave-uniform (HW adds lane*16);
// global source is per-lane.
static __device__ __forceinline__ void gload16(const void* g, void* l) {
    __builtin_amdgcn_global_load_lds(
        (const __attribute__((address_space(1))) unsigned int*)g,
        (__attribute__((address_space(3))) unsigned int*)l, 16, 0, 0);
}

// counted-vmcnt barrier pairs (T4)
static __device__ __forceinline__ void wait_vm8_bar() {
    asm volatile("s_waitcnt vmcnt(8)" ::: "memory");
    asm volatile("s_barrier" ::: "memory");
    __builtin_amdgcn_sched_barrier(0);
}
static __device__ __forceinline__ void wait_vm12_bar() {
    asm volatile("s_waitcnt vmcnt(12)" ::: "memory");
    asm volatile("s_barrier" ::: "memory");
    __builtin_amdgcn_sched_barrier(0);
}
static __device__ __forceinline__ void wait_vm0_bar() {
    asm volatile("s_waitcnt vmcnt(0)" ::: "memory");
    asm volatile("s_barrier" ::: "memory");
    __builtin_amdgcn_sched_barrier(0);
}
static __device__ __forceinline__ void bar_only() {
    asm volatile("s_barrier" ::: "memory");
}

// ---------------------------------------------------------------------------
// Kernel P: merged prep — conv3 (blocks 0..12287) | exp (12288..28671) |
// wpack (28672..28863). One launch; ~53 us clean (r17 vs r18 delta).
// ---------------------------------------------------------------------------
__global__ __launch_bounds__(256) void prep_kernel(
    const float* __restrict__ q, const float* __restrict__ k,
    const float* __restrict__ v, const float* __restrict__ dist,
    const float* __restrict__ Wq, const float* __restrict__ Wk,
    const float* __restrict__ Wv, const float* __restrict__ alpha_raw,
    unsigned short* __restrict__ Xb, unsigned short* __restrict__ ea,
    unsigned short* __restrict__ Wb)
{
    const int bid = blockIdx.x;
    if (bid < 12288) {
        const int sel = bid >> 12;
        const float* src = (sel == 0) ? q : (sel == 1) ? k : v;
        const size_t i8 = (((size_t)(bid & 4095)) * 256 + threadIdx.x) * 8;
        float4 a = *(const float4*)(src + i8);
        float4 c = *(const float4*)(src + i8 + 4);
        *(u16x8*)(Xb + (size_t)sel * NBATCH * NG * DM + i8) =
            (u16x8){ f2bf(a.x), f2bf(a.y), f2bf(a.z), f2bf(a.w),
                     f2bf(c.x), f2bf(c.y), f2bf(c.z), f2bf(c.w) };
    } else if (bid < 28672) {
        const float alpha = log1pf(__expf(alpha_raw[0])) + 1e-6f;
        const float sc = -alpha * 10.0f * 1.44269504088896f;
        const size_t i8 = (((size_t)(bid - 12288)) * 256 + threadIdx.x) * 8;
        float4 v0 = *(const float4*)(dist + i8);
        float4 v1 = *(const float4*)(dist + i8 + 4);
        *(u16x8*)(ea + i8) =
            (u16x8){ f2bf(exp2f(sc * v0.x)), f2bf(exp2f(sc * v0.y)),
                     f2bf(exp2f(sc * v0.z)), f2bf(exp2f(sc * v0.w)),
                     f2bf(exp2f(sc * v1.x)), f2bf(exp2f(sc * v1.y)),
                     f2bf(exp2f(sc * v1.z)), f2bf(exp2f(sc * v1.w)) };
    } else {
        const int i4 = ((bid - 28672) * 256 + threadIdx.x) * 4;
        const int t = i4 >> 16;
        const int off = i4 & 65535;
        const float* src = (t == 0) ? Wq : (t == 1) ? Wk : Wv;
        float4 w4 = *(const float4*)(src + off);
        *(u16x4*)(Wb + i4) = (u16x4){ f2bf(w4.x), f2bf(w4.y), f2bf(w4.z), f2bf(w4.w) };
    }
}

// ---------------------------------------------------------------------------
// Kernel Q: qb = bf16(Xq @ Wq^T + bq)  (pre-sigmoid; attn applies sigmoid).
// dbuf + counted-vmcnt (T4), proven structure.
// ---------------------------------------------------------------------------
__global__ __launch_bounds__(256) void projq_kernel(
    const unsigned short* __restrict__ Xq,   // [32768][256] bf16
    const unsigned short* __restrict__ Wb,   // [256][256] bf16 (Wq)
    const float* __restrict__ bq,
    unsigned short* __restrict__ qb)         // [32768][256] bf16
{
    __shared__ __align__(128) unsigned short lds[2][2][128 * 64];

    const int bid = blockIdx.x;
    const int mt = bid >> 1, nt = bid & 1;
    const int tid = threadIdx.x;
    const int w = tid >> 6, lane = tid & 63;
    const int wm = w >> 1, wn = w & 1;
    const int l15 = lane & 15, lhi = lane >> 4;
    const int lr = lane >> 3, sl = lane & 7;
    const int sp = sl ^ lr;

    const char* Abase = (const char*)(Xq + (size_t)mt * 128 * 256);
    const char* Wbase = (const char*)(Wb + (size_t)nt * 128 * 256);

    f32x4 acc[4][4];
    #pragma unroll
    for (int mi = 0; mi < 4; ++mi)
        #pragma unroll
        for (int ni = 0; ni < 4; ++ni)
            acc[mi][ni] = (f32x4){0.f, 0.f, 0.f, 0.f};

    auto STAGE = [&](int buf, int t) {
        #pragma unroll
        for (int i = 0; i < 4; ++i) {
            const int r = w * 32 + i * 8 + lr;
            gload16(Abase + (size_t)r * 512 + t * 128 + sp * 16,
                    (char*)&lds[buf][0][0] + w * 4096 + i * 1024);
            gload16(Wbase + (size_t)r * 512 + t * 128 + sp * 16,
                    (char*)&lds[buf][1][0] + w * 4096 + i * 1024);
        }
    };

    STAGE(0, 0);
    int cur = 0;
    for (int t = 0; t < 4; ++t) {
        if (t < 3) { STAGE(cur ^ 1, t + 1); wait_vm8_bar(); }
        else       { wait_vm0_bar(); }
        const char* Ab = (const char*)&lds[cur][0][0];
        const char* Bb = (const char*)&lds[cur][1][0];
        #pragma unroll
        for (int kk = 0; kk < 2; ++kk) {
            bf16x8 af[4], bfr[4];
            #pragma unroll
            for (int mi = 0; mi < 4; ++mi) {
                const int tr = wm * 64 + mi * 16 + l15;
                af[mi] = *(const bf16x8*)(Ab + ((tr * 128 + kk * 64 + lhi * 16) ^ ((tr & 7) << 4)));
            }
            #pragma unroll
            for (int ni = 0; ni < 4; ++ni) {
                const int tr = wn * 64 + ni * 16 + l15;
                bfr[ni] = *(const bf16x8*)(Bb + ((tr * 128 + kk * 64 + lhi * 16) ^ ((tr & 7) << 4)));
            }
            #pragma unroll
            for (int mi = 0; mi < 4; ++mi)
                #pragma unroll
                for (int ni = 0; ni < 4; ++ni)
                    acc[mi][ni] = __builtin_amdgcn_mfma_f32_16x16x32_bf16(
                        af[mi], bfr[ni], acc[mi][ni], 0, 0, 0);
        }
        bar_only();
        cur ^= 1;
    }

    #pragma unroll
    for (int ni = 0; ni < 4; ++ni) {
        const int c = nt * 128 + wn * 64 + ni * 16 + l15;
        const float bqs = bq[c];
        #pragma unroll
        for (int mi = 0; mi < 4; ++mi)
            #pragma unroll
            for (int r = 0; r < 4; ++r) {
                const size_t R = (size_t)mt * 128 + wm * 64 + mi * 16 + lhi * 4 + r;
                qb[R * DM + c] = f2bf(acc[mi][ni][r] + bqs);
            }
    }
}

// ---------------------------------------------------------------------------
// Kernel KV: k, v projections fused (row = [k 64B | v 64B]); dbuf + T4.
// Pt rows 2c/2c+1 = exp(k)*v / exp(k).
// ---------------------------------------------------------------------------
__global__ __launch_bounds__(256) void projkv_kernel(
    const unsigned short* __restrict__ Xk,
    const unsigned short* __restrict__ Xv,
    const unsigned short* __restrict__ Wkb,
    const unsigned short* __restrict__ Wvb,
    const float* __restrict__ bk, const float* __restrict__ bv,
    unsigned short* __restrict__ Pt)
{
    __shared__ __align__(128) unsigned short lds[2][2][128 * 64];

    const int bid = blockIdx.x;
    const int mt = bid >> 1, nt = bid & 1;
    const int tid = threadIdx.x;
    const int w = tid >> 6, lane = tid & 63;
    const int wm = w >> 1, wn = w & 1;
    const int l15 = lane & 15, lhi = lane >> 4;
    const int lr = lane >> 3, sl = lane & 7;
    const int sp = sl ^ lr;
    const int g16 = (sp & 3) * 16;

    f32x4 kacc[4][4], vacc[4][4];
    #pragma unroll
    for (int mi = 0; mi < 4; ++mi)
        #pragma unroll
        for (int ni = 0; ni < 4; ++ni) {
            kacc[mi][ni] = (f32x4){0.f, 0.f, 0.f, 0.f};
            vacc[mi][ni] = (f32x4){0.f, 0.f, 0.f, 0.f};
        }

    auto STAGE = [&](int buf, int t) {
        #pragma unroll
        for (int i = 0; i < 4; ++i) {
            const int r = w * 32 + i * 8 + lr;
            const char* asrc = (sp < 4 ? (const char*)Xk : (const char*)Xv)
                               + (size_t)(mt * 128 + r) * 512 + t * 64 + g16;
            gload16(asrc, (char*)&lds[buf][0][0] + w * 4096 + i * 1024);
            const char* wsrc = (sp < 4 ? (const char*)Wkb : (const char*)Wvb)
                               + (size_t)(nt * 128 + r) * 512 + t * 64 + g16;
            gload16(wsrc, (char*)&lds[buf][1][0] + w * 4096 + i * 1024);
        }
    };

    STAGE(0, 0);
    int cur = 0;
    for (int t = 0; t < 8; ++t) {
        if (t < 7) { STAGE(cur ^ 1, t + 1); wait_vm8_bar(); }
        else       { wait_vm0_bar(); }
        const char* Ab = (const char*)&lds[cur][0][0];
        const char* Bb = (const char*)&lds[cur][1][0];
        bf16x8 kaf[4], vaf[4], kbf[4], vbf[4];
        #pragma unroll
        for (int mi = 0; mi < 4; ++mi) {
            const int tr = wm * 64 + mi * 16 + l15;
            const int sw = (tr & 7) << 4;
            kaf[mi] = *(const bf16x8*)(Ab + ((tr * 128 + lhi * 16) ^ sw));
            vaf[mi] = *(const bf16x8*)(Ab + ((tr * 128 + 64 + lhi * 16) ^ sw));
        }
        #pragma unroll
        for (int ni = 0; ni < 4; ++ni) {
            const int tr = wn * 64 + ni * 16 + l15;
            const int sw = (tr & 7) << 4;
            kbf[ni] = *(const bf16x8*)(Bb + ((tr * 128 + lhi * 16) ^ sw));
            vbf[ni] = *(const bf16x8*)(Bb + ((tr * 128 + 64 + lhi * 16) ^ sw));
        }
        #pragma unroll
        for (int mi = 0; mi < 4; ++mi)
            #pragma unroll
            for (int ni = 0; ni < 4; ++ni) {
                kacc[mi][ni] = __builtin_amdgcn_mfma_f32_16x16x32_bf16(
                    kaf[mi], kbf[ni], kacc[mi][ni], 0, 0, 0);
                vacc[mi][ni] = __builtin_amdgcn_mfma_f32_16x16x32_bf16(
                    vaf[mi], vbf[ni], vacc[mi][ni], 0, 0, 0);
            }
        bar_only();
        cur ^= 1;
    }

    const int b = (mt * 128) >> 10;
    const int kb0 = (mt * 128) & 1023;
    #pragma unroll
    for (int ni = 0; ni < 4; ++ni) {
        const int c = nt * 128 + wn * 64 + ni * 16 + l15;
        const float bks = bk[c], bvs = bv[c];
        #pragma unroll
        for (int mi = 0; mi < 4; ++mi) {
            unsigned short p1[4], p2[4];
            #pragma unroll
            for (int r = 0; r < 4; ++r) {
                const float ek = __expf(kacc[mi][ni][r] + bks);
                const float vv = vacc[mi][ni][r] + bvs;
                p1[r] = f2bf(ek * vv);
                p2[r] = f2bf(ek);
            }
            const int kidx = kb0 + wm * 64 + mi * 16 + lhi * 4;
            *(u16x4*)&Pt[((size_t)b * 512 + 2 * c    ) * NG + kidx] =
                (u16x4){p1[0], p1[1], p1[2], p1[3]};
            *(u16x4*)&Pt[((size_t)b * 512 + 2 * c + 1) * NG + kidx] =
                (u16x4){p2[0], p2[1], p2[2], p2[3]};
        }
    }
}

// ---------------------------------------------------------------------------
// Kernel C: out = sigmoid(q) * (num/den). 256x256 tile, BK=64, 8 waves (2x4).
// NEW: B (Pt, XCD-L2-resident after chunk swizzle: ~4.2 MB/XCD) loaded
// DIRECTLY to registers from global, prefetched 1 K-tile ahead with static
// double register sets (manual 2-unroll, rule #20). A (ea, HBM-sized) keeps
// gload_lds dbuf (2 x 32 KB = 64 KB LDS). Halves the gload_lds/vmcnt chain:
// per thread per tile = 8 B-reg loads + 4 A gload_lds -> vmcnt(12) vouches
// the previous A tile. Proven 128B-row XOR swizzle on A (0 conflicts).
// qb-fused sigmoid epilogue. grid 256 = 32b x 4m x 2n, 1 blk/CU, XCD-chunked.
// ---------------------------------------------------------------------------
__global__ __launch_bounds__(512, 2) void attn_kernel(
    const unsigned short* __restrict__ ea,
    const unsigned short* __restrict__ Pt,
    const unsigned short* __restrict__ qb,
    float* __restrict__ out)
{
    __shared__ __align__(128) char lds[2][256 * 128];   // A only: [buf][256r x 128B]

    const int bid = blockIdx.x;
    const int l = (bid & 7) * 32 + (bid >> 3);   // XCD-chunked, bijective
    const int b = l >> 3;          // 0..31
    const int m = (l >> 1) & 3;    // 0..3
    const int n = l & 1;           // 0..1

    const int tid = threadIdx.x;
    const int w = tid >> 6, lane = tid & 63;
    const int wm = w >> 2, wn = w & 3;           // wave grid 2x4
    const int l15 = lane & 15, lhi = lane >> 4;

    // A staging: 512 threads cover 256 rows x 128B in 4 rounds of 64 rows
    const int srow = tid >> 3;                   // 0..63
    const int sg = (tid & 7) ^ (srow & 7);       // inverse-swizzled granule

    const char* Abase = (const char*)(ea + ((size_t)b * NG + m * 256) * NG);
    const char* Bbase = (const char*)(Pt + ((size_t)b * 512 + n * 256) * NG);

    f32x4 acc[8][4];
    #pragma unroll
    for (int mi = 0; mi < 8; ++mi)
        #pragma unroll
        for (int ni = 0; ni < 4; ++ni)
            acc[mi][ni] = (f32x4){0.f, 0.f, 0.f, 0.f};

    // A: stage K-tile t (256 rows x 128B) into buf: 4 gload16/thread
    auto STAGE_A = [&](int buf, int t) {
        #pragma unroll
        for (int j = 0; j < 4; ++j) {
            const int r = j * 64 + srow;
            gload16(Abase + (size_t)r * 2048 + t * 128 + sg * 16,
                    &lds[buf][0] + j * 8192 + w * 1024);
        }
    };
    // B: load 8 fragments (ni x kk) for K-tile t directly to regs
    auto BPRE = [&](int t, bf16x8 (&br)[8]) {
        #pragma unroll
        for (int ni = 0; ni < 4; ++ni) {
            const int row = wn * 64 + ni * 16 + l15;
            #pragma unroll
            for (int kk = 0; kk < 2; ++kk)
                br[ni * 2 + kk] = *(const bf16x8*)(
                    Bbase + (size_t)row * 2048 + t * 128 + kk * 64 + lhi * 16);
        }
    };
    // compute tile t: A from lds[cur], B from bc; prefetch into bn
    auto BODY = [&](int cur, int t, bf16x8 (&bc)[8], bf16x8 (&bn)[8]) {
        if (t < 15) {
            BPRE(t + 1, bn);              // 8 global loads (regs)
            STAGE_A(cur ^ 1, t + 1);      // 4 gload_lds
            wait_vm12_bar();              // prev A-tile (oldest 4) vouched
        } else {
            wait_vm0_bar();
        }
        const char* Ab = &lds[cur][0];
        __builtin_amdgcn_s_setprio(1);
        #pragma unroll
        for (int kk = 0; kk < 2; ++kk) {
            bf16x8 af[8];
            #pragma unroll
            for (int mi = 0; mi < 8; ++mi) {
                const int tr = wm * 128 + mi * 16 + l15;
                af[mi] = *(const bf16x8*)(
                    Ab + ((tr * 128 + kk * 64 + lhi * 16) ^ ((tr & 7) << 4)));
            }
            #pragma unroll
            for (int mi = 0; mi < 8; ++mi)
                #pragma unroll
                for (int ni = 0; ni < 4; ++ni)
                    acc[mi][ni] = __builtin_amdgcn_mfma_f32_16x16x32_bf16(
                        af[mi], bc[ni * 2 + kk], acc[mi][ni], 0, 0, 0);
        }
        __builtin_amdgcn_s_setprio(0);
        bar_only();
    };

    bf16x8 bA[8], bB[8];
    BPRE(0, bA);
    STAGE_A(0, 0);
    asm volatile("s_waitcnt vmcnt(0)" ::: "memory");
    __builtin_amdgcn_s_barrier();
    __builtin_amdgcn_sched_barrier(0);

    #pragma unroll 1
    for (int i = 0; i < 8; ++i) {
        BODY(0, 2 * i,     bA, bB);
        BODY(1, 2 * i + 1, bB, bA);
    }

    // epilogue: even col = numerator, odd = denominator (same d); sigmoid(q)
    const int parity = lane & 1;
    #pragma unroll
    for (int mi = 0; mi < 8; ++mi)
        #pragma unroll
        for (int ni = 0; ni < 4; ++ni)
            #pragma unroll
            for (int r = 0; r < 4; ++r) {
                const float own = acc[mi][ni][r];
                const float other = __shfl_xor(own, 1, 64);
                if (!parity) {
                    const int colg = n * 256 + wn * 64 + ni * 16 + l15;   // even
                    const int d = colg >> 1;
                    const int rowg = m * 256 + wm * 128 + mi * 16 + lhi * 4 + r;
                    const size_t idx = ((size_t)b * NG + rowg) * DM + d;
                    const float qv = bf2f(qb[idx]);
                    const float sig = 1.0f / (1.0f + __expf(-qv));
                    out[idx] = sig * (own / (other + 1e-8f));
                }
            }
}

extern "C" void kernel_launch(void* const* d_in, const int* in_sizes, int n_in,
                              void* d_out, int out_size, void* d_ws, size_t ws_size,
                              hipStream_t stream) {
    const float* query = (const float*)d_in[0];
    const float* key_  = (const float*)d_in[1];
    const float* value = (const float*)d_in[2];
    const float* dist  = (const float*)d_in[3];
    const float* Wq = (const float*)d_in[4];
    const float* bq = (const float*)d_in[5];
    const float* Wk = (const float*)d_in[6];
    const float* bk = (const float*)d_in[7];
    const float* Wv = (const float*)d_in[8];
    const float* bv = (const float*)d_in[9];
    const float* alpha_raw = (const float*)d_in[10];
    float* out = (float*)d_out;

    // ws (512 MiB): Pt 32M | ea 64M | Xb 3x16.8M | qb 16.8M | Wb 384K
    unsigned short* Pt = (unsigned short*)d_ws;
    unsigned short* ea = Pt + (size_t)NBATCH * 512 * NG;
    unsigned short* Xb = ea + (size_t)NBATCH * NG * NG;
    const size_t XN = (size_t)NBATCH * NG * DM;
    unsigned short* qb = Xb + 3 * XN;
    unsigned short* Wb = qb + XN;

    prep_kernel<<<dim3(28864), dim3(256), 0, stream>>>(
        query, key_, value, dist, Wq, Wk, Wv, alpha_raw, Xb, ea, Wb);

    projq_kernel<<<dim3(512), dim3(256), 0, stream>>>(Xb, Wb, bq, qb);
    projkv_kernel<<<dim3(512), dim3(256), 0, stream>>>(
        Xb + XN, Xb + 2 * XN, Wb + 65536, Wb + 131072, bk, bv, Pt);

    attn_kernel<<<dim3(256), dim3(512), 0, stream>>>(ea, Pt, qb, out);
}

// Round 21
// 174.080 us; speedup vs baseline: 1.4013x; 1.4013x over previous
//
#include <hip/hip_runtime.h>
#include <hip/hip_bf16.h>

#define NBATCH 32
#define NG 1024
#define DM 256

typedef short bf16x8 __attribute__((ext_vector_type(8)));
typedef float f32x4 __attribute__((ext_vector_type(4)));
typedef unsigned short u16x4 __attribute__((ext_vector_type(4)));
typedef unsigned short u16x8 __attribute__((ext_vector_type(8)));

static __device__ __forceinline__ unsigned short f2bf(float f) {
    __hip_bfloat16 h = __float2bfloat16(f);
    return *reinterpret_cast<unsigned short*>(&h);
}
static __device__ __forceinline__ float bf2f(unsigned short u) {
    unsigned int x = ((unsigned int)u) << 16;
    return *reinterpret_cast<float*>(&x);
}

// async global->LDS, 16B per lane. LDS dest wave-uniform (HW adds lane*16);
// global source is per-lane.
static __device__ __forceinline__ void gload16(const void* g, void* l) {
    __builtin_amdgcn_global_load_lds(
        (const __attribute__((address_space(1))) unsigned int*)g,
        (__attribute__((address_space(3))) unsigned int*)l, 16, 0, 0);
}

// counted-vmcnt barrier pairs (T4)
static __device__ __forceinline__ void wait_vm8_bar() {
    asm volatile("s_waitcnt vmcnt(8)" ::: "memory");
    asm volatile("s_barrier" ::: "memory");
    __builtin_amdgcn_sched_barrier(0);
}
static __device__ __forceinline__ void wait_vm0_bar() {
    asm volatile("s_waitcnt vmcnt(0)" ::: "memory");
    asm volatile("s_barrier" ::: "memory");
    __builtin_amdgcn_sched_barrier(0);
}
static __device__ __forceinline__ void bar_only() {
    asm volatile("s_barrier" ::: "memory");
}

// ---------------------------------------------------------------------------
// Kernel P: merged prep — conv3 (blocks 0..12287) | exp (12288..28671) |
// wpack (28672..28863). One launch; ~53 us clean (r17 vs r18 delta).
// ---------------------------------------------------------------------------
__global__ __launch_bounds__(256) void prep_kernel(
    const float* __restrict__ q, const float* __restrict__ k,
    const float* __restrict__ v, const float* __restrict__ dist,
    const float* __restrict__ Wq, const float* __restrict__ Wk,
    const float* __restrict__ Wv, const float* __restrict__ alpha_raw,
    unsigned short* __restrict__ Xb, unsigned short* __restrict__ ea,
    unsigned short* __restrict__ Wb)
{
    const int bid = blockIdx.x;
    if (bid < 12288) {
        const int sel = bid >> 12;
        const float* src = (sel == 0) ? q : (sel == 1) ? k : v;
        const size_t i8 = (((size_t)(bid & 4095)) * 256 + threadIdx.x) * 8;
        float4 a = *(const float4*)(src + i8);
        float4 c = *(const float4*)(src + i8 + 4);
        *(u16x8*)(Xb + (size_t)sel * NBATCH * NG * DM + i8) =
            (u16x8){ f2bf(a.x), f2bf(a.y), f2bf(a.z), f2bf(a.w),
                     f2bf(c.x), f2bf(c.y), f2bf(c.z), f2bf(c.w) };
    } else if (bid < 28672) {
        const float alpha = log1pf(__expf(alpha_raw[0])) + 1e-6f;
        const float sc = -alpha * 10.0f * 1.44269504088896f;
        const size_t i8 = (((size_t)(bid - 12288)) * 256 + threadIdx.x) * 8;
        float4 v0 = *(const float4*)(dist + i8);
        float4 v1 = *(const float4*)(dist + i8 + 4);
        *(u16x8*)(ea + i8) =
            (u16x8){ f2bf(exp2f(sc * v0.x)), f2bf(exp2f(sc * v0.y)),
                     f2bf(exp2f(sc * v0.z)), f2bf(exp2f(sc * v0.w)),
                     f2bf(exp2f(sc * v1.x)), f2bf(exp2f(sc * v1.y)),
                     f2bf(exp2f(sc * v1.z)), f2bf(exp2f(sc * v1.w)) };
    } else {
        const int i4 = ((bid - 28672) * 256 + threadIdx.x) * 4;
        const int t = i4 >> 16;
        const int off = i4 & 65535;
        const float* src = (t == 0) ? Wq : (t == 1) ? Wk : Wv;
        float4 w4 = *(const float4*)(src + off);
        *(u16x4*)(Wb + i4) = (u16x4){ f2bf(w4.x), f2bf(w4.y), f2bf(w4.z), f2bf(w4.w) };
    }
}

// ---------------------------------------------------------------------------
// Kernel Q: qb = bf16(Xq @ Wq^T + bq)  (pre-sigmoid; attn applies sigmoid).
// dbuf + counted-vmcnt (T4), proven structure.
// ---------------------------------------------------------------------------
__global__ __launch_bounds__(256) void projq_kernel(
    const unsigned short* __restrict__ Xq,   // [32768][256] bf16
    const unsigned short* __restrict__ Wb,   // [256][256] bf16 (Wq)
    const float* __restrict__ bq,
    unsigned short* __restrict__ qb)         // [32768][256] bf16
{
    __shared__ __align__(128) unsigned short lds[2][2][128 * 64];

    const int bid = blockIdx.x;
    const int mt = bid >> 1, nt = bid & 1;
    const int tid = threadIdx.x;
    const int w = tid >> 6, lane = tid & 63;
    const int wm = w >> 1, wn = w & 1;
    const int l15 = lane & 15, lhi = lane >> 4;
    const int lr = lane >> 3, sl = lane & 7;
    const int sp = sl ^ lr;

    const char* Abase = (const char*)(Xq + (size_t)mt * 128 * 256);
    const char* Wbase = (const char*)(Wb + (size_t)nt * 128 * 256);

    f32x4 acc[4][4];
    #pragma unroll
    for (int mi = 0; mi < 4; ++mi)
        #pragma unroll
        for (int ni = 0; ni < 4; ++ni)
            acc[mi][ni] = (f32x4){0.f, 0.f, 0.f, 0.f};

    auto STAGE = [&](int buf, int t) {
        #pragma unroll
        for (int i = 0; i < 4; ++i) {
            const int r = w * 32 + i * 8 + lr;
            gload16(Abase + (size_t)r * 512 + t * 128 + sp * 16,
                    (char*)&lds[buf][0][0] + w * 4096 + i * 1024);
            gload16(Wbase + (size_t)r * 512 + t * 128 + sp * 16,
                    (char*)&lds[buf][1][0] + w * 4096 + i * 1024);
        }
    };

    STAGE(0, 0);
    int cur = 0;
    for (int t = 0; t < 4; ++t) {
        if (t < 3) { STAGE(cur ^ 1, t + 1); wait_vm8_bar(); }
        else       { wait_vm0_bar(); }
        const char* Ab = (const char*)&lds[cur][0][0];
        const char* Bb = (const char*)&lds[cur][1][0];
        #pragma unroll
        for (int kk = 0; kk < 2; ++kk) {
            bf16x8 af[4], bfr[4];
            #pragma unroll
            for (int mi = 0; mi < 4; ++mi) {
                const int tr = wm * 64 + mi * 16 + l15;
                af[mi] = *(const bf16x8*)(Ab + ((tr * 128 + kk * 64 + lhi * 16) ^ ((tr & 7) << 4)));
            }
            #pragma unroll
            for (int ni = 0; ni < 4; ++ni) {
                const int tr = wn * 64 + ni * 16 + l15;
                bfr[ni] = *(const bf16x8*)(Bb + ((tr * 128 + kk * 64 + lhi * 16) ^ ((tr & 7) << 4)));
            }
            #pragma unroll
            for (int mi = 0; mi < 4; ++mi)
                #pragma unroll
                for (int ni = 0; ni < 4; ++ni)
                    acc[mi][ni] = __builtin_amdgcn_mfma_f32_16x16x32_bf16(
                        af[mi], bfr[ni], acc[mi][ni], 0, 0, 0);
        }
        bar_only();
        cur ^= 1;
    }

    #pragma unroll
    for (int ni = 0; ni < 4; ++ni) {
        const int c = nt * 128 + wn * 64 + ni * 16 + l15;
        const float bqs = bq[c];
        #pragma unroll
        for (int mi = 0; mi < 4; ++mi)
            #pragma unroll
            for (int r = 0; r < 4; ++r) {
                const size_t R = (size_t)mt * 128 + wm * 64 + mi * 16 + lhi * 4 + r;
                qb[R * DM + c] = f2bf(acc[mi][ni][r] + bqs);
            }
    }
}

// ---------------------------------------------------------------------------
// Kernel KV: k, v projections fused (row = [k 64B | v 64B]); dbuf + T4.
// Pt rows 2c/2c+1 = exp(k)*v / exp(k).
// ---------------------------------------------------------------------------
__global__ __launch_bounds__(256) void projkv_kernel(
    const unsigned short* __restrict__ Xk,
    const unsigned short* __restrict__ Xv,
    const unsigned short* __restrict__ Wkb,
    const unsigned short* __restrict__ Wvb,
    const float* __restrict__ bk, const float* __restrict__ bv,
    unsigned short* __restrict__ Pt)
{
    __shared__ __align__(128) unsigned short lds[2][2][128 * 64];

    const int bid = blockIdx.x;
    const int mt = bid >> 1, nt = bid & 1;
    const int tid = threadIdx.x;
    const int w = tid >> 6, lane = tid & 63;
    const int wm = w >> 1, wn = w & 1;
    const int l15 = lane & 15, lhi = lane >> 4;
    const int lr = lane >> 3, sl = lane & 7;
    const int sp = sl ^ lr;
    const int g16 = (sp & 3) * 16;

    f32x4 kacc[4][4], vacc[4][4];
    #pragma unroll
    for (int mi = 0; mi < 4; ++mi)
        #pragma unroll
        for (int ni = 0; ni < 4; ++ni) {
            kacc[mi][ni] = (f32x4){0.f, 0.f, 0.f, 0.f};
            vacc[mi][ni] = (f32x4){0.f, 0.f, 0.f, 0.f};
        }

    auto STAGE = [&](int buf, int t) {
        #pragma unroll
        for (int i = 0; i < 4; ++i) {
            const int r = w * 32 + i * 8 + lr;
            const char* asrc = (sp < 4 ? (const char*)Xk : (const char*)Xv)
                               + (size_t)(mt * 128 + r) * 512 + t * 64 + g16;
            gload16(asrc, (char*)&lds[buf][0][0] + w * 4096 + i * 1024);
            const char* wsrc = (sp < 4 ? (const char*)Wkb : (const char*)Wvb)
                               + (size_t)(nt * 128 + r) * 512 + t * 64 + g16;
            gload16(wsrc, (char*)&lds[buf][1][0] + w * 4096 + i * 1024);
        }
    };

    STAGE(0, 0);
    int cur = 0;
    for (int t = 0; t < 8; ++t) {
        if (t < 7) { STAGE(cur ^ 1, t + 1); wait_vm8_bar(); }
        else       { wait_vm0_bar(); }
        const char* Ab = (const char*)&lds[cur][0][0];
        const char* Bb = (const char*)&lds[cur][1][0];
        bf16x8 kaf[4], vaf[4], kbf[4], vbf[4];
        #pragma unroll
        for (int mi = 0; mi < 4; ++mi) {
            const int tr = wm * 64 + mi * 16 + l15;
            const int sw = (tr & 7) << 4;
            kaf[mi] = *(const bf16x8*)(Ab + ((tr * 128 + lhi * 16) ^ sw));
            vaf[mi] = *(const bf16x8*)(Ab + ((tr * 128 + 64 + lhi * 16) ^ sw));
        }
        #pragma unroll
        for (int ni = 0; ni < 4; ++ni) {
            const int tr = wn * 64 + ni * 16 + l15;
            const int sw = (tr & 7) << 4;
            kbf[ni] = *(const bf16x8*)(Bb + ((tr * 128 + lhi * 16) ^ sw));
            vbf[ni] = *(const bf16x8*)(Bb + ((tr * 128 + 64 + lhi * 16) ^ sw));
        }
        #pragma unroll
        for (int mi = 0; mi < 4; ++mi)
            #pragma unroll
            for (int ni = 0; ni < 4; ++ni) {
                kacc[mi][ni] = __builtin_amdgcn_mfma_f32_16x16x32_bf16(
                    kaf[mi], kbf[ni], kacc[mi][ni], 0, 0, 0);
                vacc[mi][ni] = __builtin_amdgcn_mfma_f32_16x16x32_bf16(
                    vaf[mi], vbf[ni], vacc[mi][ni], 0, 0, 0);
            }
        bar_only();
        cur ^= 1;
    }

    const int b = (mt * 128) >> 10;
    const int kb0 = (mt * 128) & 1023;
    #pragma unroll
    for (int ni = 0; ni < 4; ++ni) {
        const int c = nt * 128 + wn * 64 + ni * 16 + l15;
        const float bks = bk[c], bvs = bv[c];
        #pragma unroll
        for (int mi = 0; mi < 4; ++mi) {
            unsigned short p1[4], p2[4];
            #pragma unroll
            for (int r = 0; r < 4; ++r) {
                const float ek = __expf(kacc[mi][ni][r] + bks);
                const float vv = vacc[mi][ni][r] + bvs;
                p1[r] = f2bf(ek * vv);
                p2[r] = f2bf(ek);
            }
            const int kidx = kb0 + wm * 64 + mi * 16 + lhi * 4;
            *(u16x4*)&Pt[((size_t)b * 512 + 2 * c    ) * NG + kidx] =
                (u16x4){p1[0], p1[1], p1[2], p1[3]};
            *(u16x4*)&Pt[((size_t)b * 512 + 2 * c + 1) * NG + kidx] =
                (u16x4){p2[0], p2[1], p2[2], p2[3]};
        }
    }
}

// ---------------------------------------------------------------------------
// Kernel C: out = sigmoid(q) * (num/den). Best-measured attn (81 us):
// 256x256 tile, BK=64, 512 threads (8 waves 2x4), dbuf 128 KB LDS, counted
// vmcnt(8); proven 128B-row XOR swizzle (0 conflicts). qb-fused sigmoid
// epilogue. At the 268 MB staged-bytes / 3.3 TB/s single-block gload_lds
// bound — 9 schedule variants could not beat it. grid 256, XCD-chunked.
// ---------------------------------------------------------------------------
__global__ __launch_bounds__(512, 2) void attn_kernel(
    const unsigned short* __restrict__ ea,
    const unsigned short* __restrict__ Pt,
    const unsigned short* __restrict__ qb,
    float* __restrict__ out)
{
    __shared__ __align__(128) char lds[2][2][32768];   // [buf][A/B][256 rows x 128B]

    const int bid = blockIdx.x;
    const int l = (bid & 7) * 32 + (bid >> 3);   // XCD-chunked, bijective
    const int b = l >> 3;          // 0..31
    const int m = (l >> 1) & 3;    // 0..3
    const int n = l & 1;           // 0..1

    const int tid = threadIdx.x;
    const int w = tid >> 6, lane = tid & 63;
    const int wm = w >> 2, wn = w & 3;           // wave grid 2x4
    const int l15 = lane & 15, lhi = lane >> 4;

    // staging: waves 0-3 stage A (rows 0-255), waves 4-7 stage B; 8 instr/wave
    const int isB = w >> 2;
    const int sw = w & 3;
    const int lr = lane >> 3;                    // row within 8-row group
    const int cbs = (lane & 7) ^ lr;             // inverse-swizzled src granule

    const char* Abase = (const char*)(ea + ((size_t)b * NG + m * 256) * NG);
    const char* Bbase = (const char*)(Pt + ((size_t)b * 512 + n * 256) * NG);
    const char* Sbase = isB ? Bbase : Abase;

    f32x4 acc[8][4];
    #pragma unroll
    for (int mi = 0; mi < 8; ++mi)
        #pragma unroll
        for (int ni = 0; ni < 4; ++ni)
            acc[mi][ni] = (f32x4){0.f, 0.f, 0.f, 0.f};

    // stage K-tile t (64 bf16 = 128B per row, 256 rows) into buf
    auto STAGE = [&](int buf, int t) {
        #pragma unroll
        for (int i = 0; i < 8; ++i) {
            const int r = sw * 64 + i * 8 + lr;          // 0..255; r&7 == lr
            gload16(Sbase + (size_t)r * 2048 + t * 128 + cbs * 16,
                    &lds[buf][isB][0] + sw * 8192 + i * 1024);
        }
    };

    STAGE(0, 0);
    int cur = 0;
    for (int t = 0; t < 16; ++t) {
        if (t < 15) { STAGE(cur ^ 1, t + 1); wait_vm8_bar(); }
        else        { wait_vm0_bar(); }
        const char* Ab = &lds[cur][0][0];
        const char* Bb = &lds[cur][1][0];
        #pragma unroll
        for (int kk = 0; kk < 2; ++kk) {
            bf16x8 af[8], bfr[4];
            #pragma unroll
            for (int mi = 0; mi < 8; ++mi) {
                const int tr = wm * 128 + mi * 16 + l15;
                af[mi] = *(const bf16x8*)(Ab + ((tr * 128 + kk * 64 + lhi * 16) ^ ((tr & 7) << 4)));
            }
            #pragma unroll
            for (int ni = 0; ni < 4; ++ni) {
                const int tr = wn * 64 + ni * 16 + l15;
                bfr[ni] = *(const bf16x8*)(Bb + ((tr * 128 + kk * 64 + lhi * 16) ^ ((tr & 7) << 4)));
            }
            #pragma unroll
            for (int mi = 0; mi < 8; ++mi)
                #pragma unroll
                for (int ni = 0; ni < 4; ++ni)
                    acc[mi][ni] = __builtin_amdgcn_mfma_f32_16x16x32_bf16(
                        af[mi], bfr[ni], acc[mi][ni], 0, 0, 0);
        }
        bar_only();
        cur ^= 1;
    }

    // epilogue: even col = numerator, odd = denominator (same d); sigmoid(q)
    const int parity = lane & 1;
    #pragma unroll
    for (int mi = 0; mi < 8; ++mi)
        #pragma unroll
        for (int ni = 0; ni < 4; ++ni)
            #pragma unroll
            for (int r = 0; r < 4; ++r) {
                const float own = acc[mi][ni][r];
                const float other = __shfl_xor(own, 1, 64);
                if (!parity) {
                    const int colg = n * 256 + wn * 64 + ni * 16 + l15;   // even
                    const int d = colg >> 1;
                    const int rowg = m * 256 + wm * 128 + mi * 16 + lhi * 4 + r;
                    const size_t idx = ((size_t)b * NG + rowg) * DM + d;
                    const float qv = bf2f(qb[idx]);
                    const float sig = 1.0f / (1.0f + __expf(-qv));
                    out[idx] = sig * (own / (other + 1e-8f));
                }
            }
}

extern "C" void kernel_launch(void* const* d_in, const int* in_sizes, int n_in,
                              void* d_out, int out_size, void* d_ws, size_t ws_size,
                              hipStream_t stream) {
    const float* query = (const float*)d_in[0];
    const float* key_  = (const float*)d_in[1];
    const float* value = (const float*)d_in[2];
    const float* dist  = (const float*)d_in[3];
    const float* Wq = (const float*)d_in[4];
    const float* bq = (const float*)d_in[5];
    const float* Wk = (const float*)d_in[6];
    const float* bk = (const float*)d_in[7];
    const float* Wv = (const float*)d_in[8];
    const float* bv = (const float*)d_in[9];
    const float* alpha_raw = (const float*)d_in[10];
    float* out = (float*)d_out;

    // ws (512 MiB): Pt 32M | ea 64M | Xb 3x16.8M | qb 16.8M | Wb 384K
    unsigned short* Pt = (unsigned short*)d_ws;
    unsigned short* ea = Pt + (size_t)NBATCH * 512 * NG;
    unsigned short* Xb = ea + (size_t)NBATCH * NG * NG;
    const size_t XN = (size_t)NBATCH * NG * DM;
    unsigned short* qb = Xb + 3 * XN;
    unsigned short* Wb = qb + XN;

    prep_kernel<<<dim3(28864), dim3(256), 0, stream>>>(
        query, key_, value, dist, Wq, Wk, Wv, alpha_raw, Xb, ea, Wb);

    projq_kernel<<<dim3(512), dim3(256), 0, stream>>>(Xb, Wb, bq, qb);
    projkv_kernel<<<dim3(512), dim3(256), 0, stream>>>(
        Xb + XN, Xb + 2 * XN, Wb + 65536, Wb + 131072, bk, bv, Pt);

    attn_kernel<<<dim3(256), dim3(512), 0, stream>>>(ea, Pt, qb, out);
}